// Round 9
// baseline (7699.702 us; speedup 1.0000x reference)
//
#include <hip/hip_runtime.h>

#define H_DIM 128
#define F_IN  384

typedef __bf16 v8bf __attribute__((ext_vector_type(8)));
typedef float  v4f  __attribute__((ext_vector_type(4)));

// order-preserving float <-> uint encoding for atomicMax
__device__ __forceinline__ unsigned enc_f32(float v) {
    unsigned u = __float_as_uint(v);
    return (u & 0x80000000u) ? ~u : (u | 0x80000000u);
}
__device__ __forceinline__ float dec_f32(unsigned e) {
    if (e == 0u) return 0.0f;  // untouched node -> 0 (matches reference where())
    unsigned u = (e & 0x80000000u) ? (e & 0x7fffffffu) : ~e;
    return __uint_as_float(u);
}

// keep-alive sinks: prevent DCE of ablated phases (no instruction emitted)
__device__ __forceinline__ void keep(float x)    { asm volatile("" :: "v"(x)); }
__device__ __forceinline__ void keepu(unsigned x){ asm volatile("" :: "v"(x)); }

// W1 [F_IN][H] fp32 -> W1T [H][F_IN] bf16 ; W2 [H][H] fp32 -> W2T [H][H] bf16
__global__ __launch_bounds__(256) void wconvert(const float* __restrict__ W1,
                                                const float* __restrict__ W2,
                                                __bf16* __restrict__ W1T,
                                                __bf16* __restrict__ W2T) {
    int i = blockIdx.x * 256 + threadIdx.x;
    if (i < F_IN * H_DIM) {
        int col = i / F_IN, k = i % F_IN;
        W1T[i] = (__bf16)W1[k * H_DIM + col];
    } else if (i < F_IN * H_DIM + H_DIM * H_DIM) {
        int j = i - F_IN * H_DIM;
        int col = j / H_DIM, k = j % H_DIM;
        W2T[j] = (__bf16)W2[k * H_DIM + col];
    }
}

// r7 structure (best: 716.7us), templated for phase ablation.
// MODE 0: full kernel.  MODE 1: leaf/nidx loads only.  MODE 2: loads + wb
// staging + layer-1 MFMA + relu/hs.  MODE 3: all but the atomics.
// REPS>1 reps shift the leaf rows by 16832/rep (~26MB) so repeats re-stream
// HBM instead of hitting a warm L2; atomic addresses (idx_s) stay constant.
template <int MODE, int REPS>
__global__ __launch_bounds__(256, 4) void mlp_k(
    const float* __restrict__ leaf, const int* __restrict__ nidx,
    const __bf16* __restrict__ W1T, const __bf16* __restrict__ W2T,
    const float* __restrict__ b1, const float* __restrict__ b2,
    unsigned* __restrict__ agg, int E)
{
    __shared__ __bf16 wb[2][128][40];   // W1T k-chunk double buffer
    __shared__ __bf16 hs[64][136];      // relu hidden
    __shared__ int   idx_s[64];
    __shared__ float b1_s[H_DIM], b2_s[H_DIM];

    const int t  = threadIdx.x;
    const int w  = t >> 6;
    const int l  = t & 63;
    const int lr = l & 15;
    const int lg = l >> 4;
    const long e0 = (long)blockIdx.x * 64;

    if (t < 64) {
        long e = e0 + t;
        idx_s[t] = nidx[e < E ? e : (E - 1)];
    }
    if (t < H_DIM) { b1_s[t] = b1[t]; b2_s[t] = b2[t]; }

    const int colt = t >> 1, kht = (t & 1) * 16;
    long erow0 = e0 + w * 16 + lr;
    if (erow0 >= E) erow0 = E - 1;

    for (int rep = 0; rep < REPS; ++rep) {
        const long erow = (erow0 + (long)rep * 16832) % (long)E;
        const float* arow = leaf + erow * (long)F_IN + lg * 8;

        if constexpr (MODE == 1) {
            // pure streaming of the real access pattern (2 half-batches of 6
            // k-steps: 12 dwordx4 in flight, VGPR-safe)
#pragma unroll
            for (int h = 0; h < 2; ++h) {
                float4 X0[6], X1[6];
#pragma unroll
                for (int ks = 0; ks < 6; ++ks) {
                    X0[ks] = *(const float4*)(arow + (h * 6 + ks) * 32);
                    X1[ks] = *(const float4*)(arow + (h * 6 + ks) * 32 + 4);
                }
#pragma unroll
                for (int ks = 0; ks < 6; ++ks) {
                    keep(X0[ks].x); keep(X0[ks].y); keep(X0[ks].z); keep(X0[ks].w);
                    keep(X1[ks].x); keep(X1[ks].y); keep(X1[ks].z); keep(X1[ks].w);
                }
            }
            if (t < 64) keep((float)idx_s[t]);
        } else {
            // stage W1T chunk ks=0 into buffer 0
            {
                const v8bf* src = (const v8bf*)(W1T + colt * F_IN + kht);
                *(v8bf*)&wb[0][colt][kht]     = src[0];
                *(v8bf*)&wb[0][colt][kht + 8] = src[1];
            }
            const v4f vzero = {0.f, 0.f, 0.f, 0.f};
            v4f acc[8];
#pragma unroll
            for (int f = 0; f < 8; ++f) acc[f] = vzero;

            float4 A0[4], A1[4];
#pragma unroll
            for (int p = 0; p < 4; ++p) {
                A0[p] = *(const float4*)(arow + p * 32);
                A1[p] = *(const float4*)(arow + p * 32 + 4);
            }
            __syncthreads();

            // ---- layer 1: K=384 in 12 steps ----
#pragma unroll
            for (int ks = 0; ks < 12; ++ks) {
                if (ks + 1 < 12) {
                    const v8bf* src = (const v8bf*)(W1T + colt * F_IN + (ks + 1) * 32 + kht);
                    const int b = (ks + 1) & 1;
                    *(v8bf*)&wb[b][colt][kht]     = src[0];
                    *(v8bf*)&wb[b][colt][kht + 8] = src[1];
                }
                v8bf af;
                af[0] = (__bf16)A0[ks & 3].x; af[1] = (__bf16)A0[ks & 3].y;
                af[2] = (__bf16)A0[ks & 3].z; af[3] = (__bf16)A0[ks & 3].w;
                af[4] = (__bf16)A1[ks & 3].x; af[5] = (__bf16)A1[ks & 3].y;
                af[6] = (__bf16)A1[ks & 3].z; af[7] = (__bf16)A1[ks & 3].w;
                if (ks + 4 < 12) {
                    A0[ks & 3] = *(const float4*)(arow + (ks + 4) * 32);
                    A1[ks & 3] = *(const float4*)(arow + (ks + 4) * 32 + 4);
                }
                const int cb = ks & 1;
#pragma unroll
                for (int f = 0; f < 8; ++f) {
                    v8bf bfv = *(const v8bf*)&wb[cb][f * 16 + lr][lg * 8];
                    acc[f] = __builtin_amdgcn_mfma_f32_16x16x32_bf16(af, bfv, acc[f], 0, 0, 0);
                }
                __syncthreads();
            }

            // ---- relu + bias -> hs ----
#pragma unroll
            for (int f = 0; f < 8; ++f) {
                const float bb = b1_s[f * 16 + lr];
#pragma unroll
                for (int j = 0; j < 4; ++j) {
                    float v = fmaxf(acc[f][j] + bb, 0.0f);
                    hs[w * 16 + lg * 4 + j][f * 16 + lr] = (__bf16)v;
                }
            }
            __syncthreads();

            if constexpr (MODE == 2) {
                keep((float)hs[w * 16 + lr][lg * 8]);   // hs live; stop here
            } else {
                // ---- layer 2 ----
                v4f acc2[8];
#pragma unroll
                for (int f = 0; f < 8; ++f) acc2[f] = vzero;
#pragma unroll
                for (int ks = 0; ks < 4; ++ks) {
                    v8bf af2 = *(const v8bf*)&hs[w * 16 + lr][ks * 32 + lg * 8];
#pragma unroll
                    for (int f = 0; f < 8; ++f) {
                        v8bf bfv = *(const v8bf*)(W2T + (f * 16 + lr) * H_DIM + ks * 32 + lg * 8);
                        acc2[f] = __builtin_amdgcn_mfma_f32_16x16x32_bf16(af2, bfv, acc2[f], 0, 0, 0);
                    }
                }
                // ---- epilogue ----
                const int rb = w * 16 + lg * 4;
#pragma unroll
                for (int j = 0; j < 4; ++j) {
                    const long ej = e0 + rb + j;
                    if (ej < E) {
                        const int node = idx_s[rb + j];
                        unsigned* dst = agg + (long)node * H_DIM + lr;
#pragma unroll
                        for (int f = 0; f < 8; ++f) {
                            float v = acc2[f][j] + b2_s[f * 16 + lr];
                            unsigned en = enc_f32(v);
                            if constexpr (MODE == 3) keepu(en);
                            else atomicMax(dst + f * 16, en);
                        }
                    }
                }
            }
        }
    }
}

// one wave per node row: lang = center + dec(agg); out = cos(gcn, lang)
__global__ __launch_bounds__(256) void cos_kernel(
    const float* __restrict__ center, const float* __restrict__ gcn,
    const unsigned* __restrict__ agg, float* __restrict__ out, int N)
{
    const int w = threadIdx.x >> 6, l = threadIdx.x & 63;
    const long row = (long)blockIdx.x * 4 + w;
    if (row >= N) return;
    const float2 g2 = *(const float2*)(gcn    + row * H_DIM + l * 2);
    const float2 c2 = *(const float2*)(center + row * H_DIM + l * 2);
    const uint2  e2 = *(const uint2*) (agg    + row * H_DIM + l * 2);
    const float l0 = c2.x + dec_f32(e2.x);
    const float l1 = c2.y + dec_f32(e2.y);
    float sgl = g2.x * l0 + g2.y * l1;
    float sgg = g2.x * g2.x + g2.y * g2.y;
    float sll = l0 * l0 + l1 * l1;
#pragma unroll
    for (int off = 32; off; off >>= 1) {
        sgl += __shfl_xor(sgl, off);
        sgg += __shfl_xor(sgg, off);
        sll += __shfl_xor(sll, off);
    }
    if (l == 0) {
        const float na = fmaxf(sqrtf(sgg), 1e-8f);
        const float nb = fmaxf(sqrtf(sll), 1e-8f);
        out[row] = sgl / (na * nb);
    }
}

extern "C" void kernel_launch(void* const* d_in, const int* in_sizes, int n_in,
                              void* d_out, int out_size, void* d_ws, size_t ws_size,
                              hipStream_t stream) {
    const float* center = (const float*)d_in[0];
    const float* leaf   = (const float*)d_in[1];
    const int*   nidx   = (const int*)  d_in[2];
    const float* gcn    = (const float*)d_in[3];
    const float* W1     = (const float*)d_in[4];
    const float* b1     = (const float*)d_in[5];
    const float* W2     = (const float*)d_in[6];
    const float* b2     = (const float*)d_in[7];

    const int E = in_sizes[2];             // 1,000,000
    const int N = in_sizes[0] / H_DIM;     // 65,536

    unsigned* agg = (unsigned*)d_ws;
    const size_t aggBytes = (size_t)N * H_DIM * sizeof(unsigned);
    __bf16* W1T = (__bf16*)((char*)d_ws + aggBytes);
    __bf16* W2T = W1T + (size_t)F_IN * H_DIM;

    const int nb = (E + 63) / 64;

    hipMemsetAsync(agg, 0, aggBytes, stream);
    wconvert<<<(F_IN * H_DIM + H_DIM * H_DIM + 255) / 256, 256, 0, stream>>>(W1, W2, W1T, W2T);
    // real pipeline (identical to r7 best)
    mlp_k<0, 1><<<nb, 256, 0, stream>>>(leaf, nidx, W1T, W2T, b1, b2, agg, E);
    cos_kernel<<<(N + 3) / 4, 256, 0, stream>>>(center, gcn, agg, (float*)d_out, N);
    // ---- instrumentation dispatches (post-output; agg scribbles reset by next
    // replay's memset; rep-shifted addresses defeat L2 warmth) ----
    mlp_k<1, 5><<<nb, 256, 0, stream>>>(leaf, nidx, W1T, W2T, b1, b2, agg, E);  // V1 loads
    mlp_k<2, 3><<<nb, 256, 0, stream>>>(leaf, nidx, W1T, W2T, b1, b2, agg, E);  // V2 +layer1
    mlp_k<3, 2><<<nb, 256, 0, stream>>>(leaf, nidx, W1T, W2T, b1, b2, agg, E);  // V3 -atomics
    mlp_k<0, 2><<<nb, 256, 0, stream>>>(leaf, nidx, W1T, W2T, b1, b2, agg, E);  // V4 full
}

// Round 10
// 1839.796 us; speedup vs baseline: 4.1851x; 4.1851x over previous
//
#include <hip/hip_runtime.h>

#define H_DIM 128
#define F_IN  384

typedef __bf16 v8bf __attribute__((ext_vector_type(8)));
typedef __bf16 v4bf __attribute__((ext_vector_type(4)));
typedef float  v4f  __attribute__((ext_vector_type(4)));

// order-preserving float <-> uint encoding for atomicMax
__device__ __forceinline__ unsigned enc_f32(float v) {
    unsigned u = __float_as_uint(v);
    return (u & 0x80000000u) ? ~u : (u | 0x80000000u);
}
__device__ __forceinline__ float dec_f32(unsigned e) {
    if (e == 0u) return 0.0f;  // untouched node -> 0 (matches reference where())
    unsigned u = (e & 0x80000000u) ? (e & 0x7fffffffu) : ~e;
    return __uint_as_float(u);
}

// LDS-only barrier: drains own LDS ops + syncs; does NOT drain vmcnt
// (prev-tile atomics stay in flight). Proven correct in r8.
__device__ __forceinline__ void lds_barrier() {
    asm volatile("s_waitcnt lgkmcnt(0)" ::: "memory");
    __builtin_amdgcn_s_barrier();
    asm volatile("" ::: "memory");
}

// W1 [F_IN][H] fp32 -> W1T [H][F_IN] bf16 ; W2 [H][H] fp32 -> W2T [H][H] bf16
__global__ __launch_bounds__(256) void wconvert(const float* __restrict__ W1,
                                                const float* __restrict__ W2,
                                                __bf16* __restrict__ W1T,
                                                __bf16* __restrict__ W2T) {
    int i = blockIdx.x * 256 + threadIdx.x;
    if (i < F_IN * H_DIM) {
        int col = i / F_IN, k = i % F_IN;
        W1T[i] = (__bf16)W1[k * H_DIM + col];
    } else if (i < F_IN * H_DIM + H_DIM * H_DIM) {
        int j = i - F_IN * H_DIM;
        int col = j / H_DIM, k = j % H_DIM;
        W2T[j] = (__bf16)W2[k * H_DIM + col];
    }
}

// Weight-stationary flipped MFMA: D = W1slice^T-frag (A) x leaf (B).
// 256 threads / 4 waves; wave w owns output cols 32w..32w+31 (2 f-blocks,
// W1 slice resident in 96 VGPR) for ALL 64 edges of the tile. Layer 1 has
// NO LDS and NO barriers; h crosses waves once via XOR-swizzled hs with one
// lgkm-only barrier per tile. 4 consecutive tiles per block amortize W1 load.
__global__ __launch_bounds__(256, 2) void mlp_scatter(
    const float* __restrict__ leaf, const int* __restrict__ nidx,
    const __bf16* __restrict__ W1T, const __bf16* __restrict__ W2T,
    const float* __restrict__ b1, const float* __restrict__ b2,
    unsigned* __restrict__ agg, int E)
{
    __shared__ __bf16 hs[2][64][136];   // double-buffered hidden, XOR-swizzled chunks

    const int t  = threadIdx.x;
    const int w  = t >> 6;
    const int l  = t & 63;
    const int lr = l & 15;    // fragment row/col index
    const int lg = l >> 4;    // k-group
    const int C0 = w * 2;     // this wave's first 16-col block

    // ---- stationary W1 A-frags: lane l holds W1T[(C0+f)*16+lr][ks*32+lg*8 ..+7] ----
    v8bf w1a[2][12];
#pragma unroll
    for (int f = 0; f < 2; ++f)
#pragma unroll
        for (int ks = 0; ks < 12; ++ks)
            w1a[f][ks] = *(const v8bf*)(W1T + ((C0 + f) * 16 + lr) * F_IN + ks * 32 + lg * 8);

    float bb1[2][4], bb2[2][4];
#pragma unroll
    for (int f = 0; f < 2; ++f)
#pragma unroll
        for (int j = 0; j < 4; ++j) {
            bb1[f][j] = b1[(C0 + f) * 16 + lg * 4 + j];
            bb2[f][j] = b2[(C0 + f) * 16 + lg * 4 + j];
        }

    const v4f vzero = {0.f, 0.f, 0.f, 0.f};
    int cur = 0;

    for (int ti = 0; ti < 4; ++ti) {
        const long e0 = ((long)blockIdx.x * 4 + ti) * 64;
        if (e0 >= E) break;

        const float* pg[4];
        int nd[4];
#pragma unroll
        for (int g = 0; g < 4; ++g) {
            long er = e0 + g * 16 + lr;
            if (er >= E) er = E - 1;           // clamp; epilogue masks
            pg[g] = leaf + er * (long)F_IN + lg * 8;
            nd[g] = nidx[er];
        }

        // ---- layer 1: no LDS, no barriers; 2-deep rolling leaf prefetch ----
        v4f acc1[2][4];
#pragma unroll
        for (int f = 0; f < 2; ++f)
#pragma unroll
            for (int g = 0; g < 4; ++g) acc1[f][g] = vzero;

        float4 cA[4], cB[4];
#pragma unroll
        for (int g = 0; g < 4; ++g) {
            cA[g] = *(const float4*)(pg[g]);
            cB[g] = *(const float4*)(pg[g] + 4);
        }
#pragma unroll
        for (int ks = 0; ks < 12; ++ks) {
            float4 nA[4], nB[4];
            if (ks + 1 < 12) {
#pragma unroll
                for (int g = 0; g < 4; ++g) {
                    nA[g] = *(const float4*)(pg[g] + (ks + 1) * 32);
                    nB[g] = *(const float4*)(pg[g] + (ks + 1) * 32 + 4);
                }
            }
            v8bf af[4];
#pragma unroll
            for (int g = 0; g < 4; ++g) {
                af[g][0] = (__bf16)cA[g].x; af[g][1] = (__bf16)cA[g].y;
                af[g][2] = (__bf16)cA[g].z; af[g][3] = (__bf16)cA[g].w;
                af[g][4] = (__bf16)cB[g].x; af[g][5] = (__bf16)cB[g].y;
                af[g][6] = (__bf16)cB[g].z; af[g][7] = (__bf16)cB[g].w;
            }
#pragma unroll
            for (int g = 0; g < 4; ++g) {
                acc1[0][g] = __builtin_amdgcn_mfma_f32_16x16x32_bf16(w1a[0][ks], af[g], acc1[0][g], 0, 0, 0);
                acc1[1][g] = __builtin_amdgcn_mfma_f32_16x16x32_bf16(w1a[1][ks], af[g], acc1[1][g], 0, 0, 0);
            }
            if (ks + 1 < 12) {
#pragma unroll
                for (int g = 0; g < 4; ++g) { cA[g] = nA[g]; cB[g] = nB[g]; }
            }
        }

        // ---- relu + bias -> hs (lane l holds h[edge=g*16+lr][hcol=(C0+f)*16+lg*4+j]) ----
        // XOR-swizzle 16B chunks: chunk ^= (row&7)  (T2 involution, both sides)
#pragma unroll
        for (int f = 0; f < 2; ++f)
#pragma unroll
            for (int g = 0; g < 4; ++g) {
                v4bf hv;
#pragma unroll
                for (int j = 0; j < 4; ++j)
                    hv[j] = (__bf16)fmaxf(acc1[f][g][j] + bb1[f][j], 0.0f);
                const int row = g * 16 + lr;
                const int ch  = (2 * (C0 + f) + (lg >> 1)) ^ (row & 7);
                *(v4bf*)&hs[cur][row][ch * 8 + (lg & 1) * 4] = hv;
            }
        lds_barrier();   // one LDS-only barrier per tile

        // ---- layer 2: A = W2 frags (L1/L2), B = h frags from hs ----
        v4f acc2[2][4];
#pragma unroll
        for (int f = 0; f < 2; ++f)
#pragma unroll
            for (int g = 0; g < 4; ++g) acc2[f][g] = vzero;
#pragma unroll
        for (int ks2 = 0; ks2 < 4; ++ks2) {
            v8bf w2f0 = *(const v8bf*)(W2T + ((C0 + 0) * 16 + lr) * H_DIM + ks2 * 32 + lg * 8);
            v8bf w2f1 = *(const v8bf*)(W2T + ((C0 + 1) * 16 + lr) * H_DIM + ks2 * 32 + lg * 8);
#pragma unroll
            for (int g = 0; g < 4; ++g) {
                const int row = g * 16 + lr;
                const int ch  = (4 * ks2 + lg) ^ (row & 7);
                v8bf hb = *(const v8bf*)&hs[cur][row][ch * 8];
                acc2[0][g] = __builtin_amdgcn_mfma_f32_16x16x32_bf16(w2f0, hb, acc2[0][g], 0, 0, 0);
                acc2[1][g] = __builtin_amdgcn_mfma_f32_16x16x32_bf16(w2f1, hb, acc2[1][g], 0, 0, 0);
            }
        }

        // ---- epilogue: + b2, scatter-max (lane l: edge g*16+lr, cols (C0+f)*16+lg*4+j) ----
#pragma unroll
        for (int g = 0; g < 4; ++g) {
            if (e0 + g * 16 + lr < E) {
                unsigned* dst = agg + (long)nd[g] * H_DIM;
#pragma unroll
                for (int f = 0; f < 2; ++f)
#pragma unroll
                    for (int j = 0; j < 4; ++j)
                        atomicMax(dst + (C0 + f) * 16 + lg * 4 + j,
                                  enc_f32(acc2[f][g][j] + bb2[f][j]));
            }
        }
        cur ^= 1;
    }
}

// one wave per node row: lang = center + dec(agg); out = cos(gcn, lang)
__global__ __launch_bounds__(256) void cos_kernel(
    const float* __restrict__ center, const float* __restrict__ gcn,
    const unsigned* __restrict__ agg, float* __restrict__ out, int N)
{
    const int w = threadIdx.x >> 6, l = threadIdx.x & 63;
    const long row = (long)blockIdx.x * 4 + w;
    if (row >= N) return;
    const float2 g2 = *(const float2*)(gcn    + row * H_DIM + l * 2);
    const float2 c2 = *(const float2*)(center + row * H_DIM + l * 2);
    const uint2  e2 = *(const uint2*) (agg    + row * H_DIM + l * 2);
    const float l0 = c2.x + dec_f32(e2.x);
    const float l1 = c2.y + dec_f32(e2.y);
    float sgl = g2.x * l0 + g2.y * l1;
    float sgg = g2.x * g2.x + g2.y * g2.y;
    float sll = l0 * l0 + l1 * l1;
#pragma unroll
    for (int off = 32; off; off >>= 1) {
        sgl += __shfl_xor(sgl, off);
        sgg += __shfl_xor(sgg, off);
        sll += __shfl_xor(sll, off);
    }
    if (l == 0) {
        const float na = fmaxf(sqrtf(sgg), 1e-8f);
        const float nb = fmaxf(sqrtf(sll), 1e-8f);
        out[row] = sgl / (na * nb);
    }
}

extern "C" void kernel_launch(void* const* d_in, const int* in_sizes, int n_in,
                              void* d_out, int out_size, void* d_ws, size_t ws_size,
                              hipStream_t stream) {
    const float* center = (const float*)d_in[0];
    const float* leaf   = (const float*)d_in[1];
    const int*   nidx   = (const int*)  d_in[2];
    const float* gcn    = (const float*)d_in[3];
    const float* W1     = (const float*)d_in[4];
    const float* b1     = (const float*)d_in[5];
    const float* W2     = (const float*)d_in[6];
    const float* b2     = (const float*)d_in[7];

    const int E = in_sizes[2];             // 1,000,000
    const int N = in_sizes[0] / H_DIM;     // 65,536

    unsigned* agg = (unsigned*)d_ws;
    const size_t aggBytes = (size_t)N * H_DIM * sizeof(unsigned);
    __bf16* W1T = (__bf16*)((char*)d_ws + aggBytes);
    __bf16* W2T = W1T + (size_t)F_IN * H_DIM;

    hipMemsetAsync(agg, 0, aggBytes, stream);
    wconvert<<<(F_IN * H_DIM + H_DIM * H_DIM + 255) / 256, 256, 0, stream>>>(W1, W2, W1T, W2T);
    mlp_scatter<<<(E + 255) / 256, 256, 0, stream>>>(leaf, nidx, W1T, W2T, b1, b2, agg, E);
    cos_kernel<<<(N + 3) / 4, 256, 0, stream>>>(center, gcn, agg, (float*)d_out, N);
}

// Round 11
// 657.164 us; speedup vs baseline: 11.7166x; 2.7996x over previous
//
#include <hip/hip_runtime.h>

#define H_DIM 128
#define F_IN  384

typedef __bf16 v8bf __attribute__((ext_vector_type(8)));
typedef float  v4f  __attribute__((ext_vector_type(4)));

// order-preserving float <-> uint encoding for atomicMax
__device__ __forceinline__ unsigned enc_f32(float v) {
    unsigned u = __float_as_uint(v);
    return (u & 0x80000000u) ? ~u : (u | 0x80000000u);
}
__device__ __forceinline__ float dec_f32(unsigned e) {
    if (e == 0u) return 0.0f;  // untouched node -> 0 (matches reference where())
    unsigned u = (e & 0x80000000u) ? (e & 0x7fffffffu) : ~e;
    return __uint_as_float(u);
}

// W1 [F_IN][H] fp32 -> W1T [H][F_IN] bf16 ; W2 [H][H] fp32 -> W2T [H][H] bf16
__global__ __launch_bounds__(256) void wconvert(const float* __restrict__ W1,
                                                const float* __restrict__ W2,
                                                __bf16* __restrict__ W1T,
                                                __bf16* __restrict__ W2T) {
    int i = blockIdx.x * 256 + threadIdx.x;
    if (i < F_IN * H_DIM) {
        int col = i / F_IN, k = i % F_IN;
        W1T[i] = (__bf16)W1[k * H_DIM + col];
    } else if (i < F_IN * H_DIM + H_DIM * H_DIM) {
        int j = i - F_IN * H_DIM;
        int col = j / H_DIM, k = j % H_DIM;
        W2T[j] = (__bf16)W2[k * H_DIM + col];
    }
}

// 128 edges per block, 256 threads (4 waves). Wave w owns edges w*32..w*32+31
// as two 16-row A-groups (A/B); every W1/W2 B-fragment is loaded once and fed
// to two MFMAs -> halves ds_read, wb-staging, and barrier count per edge
// (r1 structure, WITHOUT r1's read-filter epilogue — fire-and-forget atomics).
__global__ __launch_bounds__(256) void mlp_scatter(
    const float* __restrict__ leaf, const int* __restrict__ nidx,
    const __bf16* __restrict__ W1T, const __bf16* __restrict__ W2T,
    const float* __restrict__ b1, const float* __restrict__ b2,
    unsigned* __restrict__ agg, int E)
{
    __shared__ __bf16 wb[2][128][40];   // W1T k-chunk double buffer (pad 40 -> 2-way max)
    __shared__ __bf16 hs[128][136];     // relu hidden, bf16 (pad 136 -> 2-way max)
    __shared__ int   idx_s[128];
    __shared__ float b1_s[H_DIM], b2_s[H_DIM];

    const int t  = threadIdx.x;
    const int w  = t >> 6;
    const int l  = t & 63;
    const int lr = l & 15;   // row/col within fragment
    const int lg = l >> 4;   // k-group
    const long e0 = (long)blockIdx.x * 128;

    if (t < 128) {
        long e = e0 + t;
        idx_s[t] = nidx[e < E ? e : (E - 1)];
    }
    if (t < H_DIM) { b1_s[t] = b1[t]; b2_s[t] = b2[t]; }

    // stage W1T chunk ks=0 into buffer 0 (each thread: 32B of one column)
    {
        const int col = t >> 1, kh = (t & 1) * 16;
        const v8bf* src = (const v8bf*)(W1T + col * F_IN + kh);
        *(v8bf*)&wb[0][col][kh]     = src[0];
        *(v8bf*)&wb[0][col][kh + 8] = src[1];
    }

    long erA = e0 + w * 32 + lr;        // group A rows
    long erB = e0 + w * 32 + 16 + lr;   // group B rows
    if (erA >= E) erA = E - 1;          // clamp (tail-safe)
    if (erB >= E) erB = E - 1;
    const float* arowA = leaf + erA * (long)F_IN + lg * 8;
    const float* arowB = leaf + erB * (long)F_IN + lg * 8;

    const v4f vzero = {0.f, 0.f, 0.f, 0.f};
    v4f accA[8], accB[8];
#pragma unroll
    for (int f = 0; f < 8; ++f) { accA[f] = vzero; accB[f] = vzero; }

    float4 aA0 = *(const float4*)(arowA);
    float4 aA1 = *(const float4*)(arowA + 4);
    float4 aB0 = *(const float4*)(arowB);
    float4 aB1 = *(const float4*)(arowB + 4);
    __syncthreads();

    // ---- layer 1: h = x @ W1, K=384 in 12 steps of 32 ----
    for (int ks = 0; ks < 12; ++ks) {
        float4 nA0 = aA0, nA1 = aA1, nB0 = aB0, nB1 = aB1;
        if (ks + 1 < 12) {
            nA0 = *(const float4*)(arowA + (ks + 1) * 32);
            nA1 = *(const float4*)(arowA + (ks + 1) * 32 + 4);
            nB0 = *(const float4*)(arowB + (ks + 1) * 32);
            nB1 = *(const float4*)(arowB + (ks + 1) * 32 + 4);
            const int col = t >> 1, kh = (t & 1) * 16;
            const v8bf* src = (const v8bf*)(W1T + col * F_IN + (ks + 1) * 32 + kh);
            const int b = (ks + 1) & 1;
            *(v8bf*)&wb[b][col][kh]     = src[0];
            *(v8bf*)&wb[b][col][kh + 8] = src[1];
        }
        v8bf afA, afB;
        afA[0] = (__bf16)aA0.x; afA[1] = (__bf16)aA0.y; afA[2] = (__bf16)aA0.z; afA[3] = (__bf16)aA0.w;
        afA[4] = (__bf16)aA1.x; afA[5] = (__bf16)aA1.y; afA[6] = (__bf16)aA1.z; afA[7] = (__bf16)aA1.w;
        afB[0] = (__bf16)aB0.x; afB[1] = (__bf16)aB0.y; afB[2] = (__bf16)aB0.z; afB[3] = (__bf16)aB0.w;
        afB[4] = (__bf16)aB1.x; afB[5] = (__bf16)aB1.y; afB[6] = (__bf16)aB1.z; afB[7] = (__bf16)aB1.w;
        const int cb = ks & 1;
#pragma unroll
        for (int f = 0; f < 8; ++f) {
            v8bf bfv = *(const v8bf*)&wb[cb][f * 16 + lr][lg * 8];
            accA[f] = __builtin_amdgcn_mfma_f32_16x16x32_bf16(afA, bfv, accA[f], 0, 0, 0);
            accB[f] = __builtin_amdgcn_mfma_f32_16x16x32_bf16(afB, bfv, accB[f], 0, 0, 0);
        }
        aA0 = nA0; aA1 = nA1; aB0 = nB0; aB1 = nB1;
        __syncthreads();
    }

    // ---- relu + bias -> bf16 hidden in LDS ----
#pragma unroll
    for (int f = 0; f < 8; ++f) {
        const float bb = b1_s[f * 16 + lr];
#pragma unroll
        for (int j = 0; j < 4; ++j) {
            float vA = fmaxf(accA[f][j] + bb, 0.0f);
            float vB = fmaxf(accB[f][j] + bb, 0.0f);
            hs[w * 32 + lg * 4 + j][f * 16 + lr]      = (__bf16)vA;
            hs[w * 32 + 16 + lg * 4 + j][f * 16 + lr] = (__bf16)vB;
        }
    }
    __syncthreads();

    // ---- layer 2: m = h @ W2, K=128 in 4 steps; W2T frags from L1/L2, reused x2 ----
    v4f acc2A[8], acc2B[8];
#pragma unroll
    for (int f = 0; f < 8; ++f) { acc2A[f] = vzero; acc2B[f] = vzero; }
#pragma unroll
    for (int ks = 0; ks < 4; ++ks) {
        v8bf afA2 = *(const v8bf*)&hs[w * 32 + lr][ks * 32 + lg * 8];
        v8bf afB2 = *(const v8bf*)&hs[w * 32 + 16 + lr][ks * 32 + lg * 8];
#pragma unroll
        for (int f = 0; f < 8; ++f) {
            v8bf bfv = *(const v8bf*)(W2T + (f * 16 + lr) * H_DIM + ks * 32 + lg * 8);
            acc2A[f] = __builtin_amdgcn_mfma_f32_16x16x32_bf16(afA2, bfv, acc2A[f], 0, 0, 0);
            acc2B[f] = __builtin_amdgcn_mfma_f32_16x16x32_bf16(afB2, bfv, acc2B[f], 0, 0, 0);
        }
    }

    // ---- epilogue: + b2, encode, fire-and-forget scatter-max ----
#pragma unroll
    for (int g = 0; g < 2; ++g) {
        const int rb = w * 32 + g * 16 + lg * 4;
#pragma unroll
        for (int j = 0; j < 4; ++j) {
            const long ej = e0 + rb + j;
            if (ej < E) {
                const int node = idx_s[rb + j];
                unsigned* dst = agg + (long)node * H_DIM + lr;
#pragma unroll
                for (int f = 0; f < 8; ++f) {
                    float v = (g ? acc2B[f][j] : acc2A[f][j]) + b2_s[f * 16 + lr];
                    atomicMax(dst + f * 16, enc_f32(v));
                }
            }
        }
    }
}

// one wave per node row: lang = center + dec(agg); out = cos(gcn, lang)
__global__ __launch_bounds__(256) void cos_kernel(
    const float* __restrict__ center, const float* __restrict__ gcn,
    const unsigned* __restrict__ agg, float* __restrict__ out, int N)
{
    const int w = threadIdx.x >> 6, l = threadIdx.x & 63;
    const long row = (long)blockIdx.x * 4 + w;
    if (row >= N) return;
    const float2 g2 = *(const float2*)(gcn    + row * H_DIM + l * 2);
    const float2 c2 = *(const float2*)(center + row * H_DIM + l * 2);
    const uint2  e2 = *(const uint2*) (agg    + row * H_DIM + l * 2);
    const float l0 = c2.x + dec_f32(e2.x);
    const float l1 = c2.y + dec_f32(e2.y);
    float sgl = g2.x * l0 + g2.y * l1;
    float sgg = g2.x * g2.x + g2.y * g2.y;
    float sll = l0 * l0 + l1 * l1;
#pragma unroll
    for (int off = 32; off; off >>= 1) {
        sgl += __shfl_xor(sgl, off);
        sgg += __shfl_xor(sgg, off);
        sll += __shfl_xor(sll, off);
    }
    if (l == 0) {
        const float na = fmaxf(sqrtf(sgg), 1e-8f);
        const float nb = fmaxf(sqrtf(sll), 1e-8f);
        out[row] = sgl / (na * nb);
    }
}

extern "C" void kernel_launch(void* const* d_in, const int* in_sizes, int n_in,
                              void* d_out, int out_size, void* d_ws, size_t ws_size,
                              hipStream_t stream) {
    const float* center = (const float*)d_in[0];
    const float* leaf   = (const float*)d_in[1];
    const int*   nidx   = (const int*)  d_in[2];
    const float* gcn    = (const float*)d_in[3];
    const float* W1     = (const float*)d_in[4];
    const float* b1     = (const float*)d_in[5];
    const float* W2     = (const float*)d_in[6];
    const float* b2     = (const float*)d_in[7];

    const int E = in_sizes[2];             // 1,000,000
    const int N = in_sizes[0] / H_DIM;     // 65,536

    unsigned* agg = (unsigned*)d_ws;
    const size_t aggBytes = (size_t)N * H_DIM * sizeof(unsigned);
    __bf16* W1T = (__bf16*)((char*)d_ws + aggBytes);
    __bf16* W2T = W1T + (size_t)F_IN * H_DIM;

    hipMemsetAsync(agg, 0, aggBytes, stream);
    wconvert<<<(F_IN * H_DIM + H_DIM * H_DIM + 255) / 256, 256, 0, stream>>>(W1, W2, W1T, W2T);
    mlp_scatter<<<(E + 127) / 128, 256, 0, stream>>>(leaf, nidx, W1T, W2T, b1, b2, agg, E);
    cos_kernel<<<(N + 3) / 4, 256, 0, stream>>>(center, gcn, agg, (float*)d_out, N);
}